// Round 11
// baseline (758.972 us; speedup 1.0000x reference)
//
#include <hip/hip_runtime.h>
#include <math.h>

#define NN 50000
#define NE 800000
#define NEG_SLOPE 0.2f
#define LN_EPS 1e-5f
#define SROW 264  // LDS stage row stride in ushorts (256 + 8 pad)

typedef unsigned short ushort_t;
typedef unsigned int uint_t;
typedef __attribute__((ext_vector_type(8))) short bf16x8;
typedef __attribute__((ext_vector_type(4))) float f32x4;

__device__ __forceinline__ float bf2f(ushort_t u) {
    return __uint_as_float(((uint_t)u) << 16);
}
__device__ __forceinline__ ushort_t f2bf(float f) {
    uint_t b = __float_as_uint(f);
    uint_t r = (b + 0x7fffu + ((b >> 16) & 1u)) >> 16;
    return (ushort_t)r;
}
__device__ __forceinline__ float ldx(const void* p, size_t i, int isbf) {
    return isbf ? bf2f(((const ushort_t*)p)[i]) : ((const float*)p)[i];
}
__device__ __forceinline__ int clampN(int v) {
    return v < 0 ? 0 : (v >= NN ? NN - 1 : v);
}
__device__ __forceinline__ int ld_src(const int* ei, int e, int f64) {
    return clampN(f64 ? ei[2 * e] : ei[e]);
}
__device__ __forceinline__ int ld_dst(const int* ei, int e, int f64) {
    return clampN(f64 ? ei[2 * NE + 2 * e] : ei[NE + e]);
}
// dtype/index sniffing, callable per-block (cheap, L1-hot)
__device__ __forceinline__ int sniff_isbf(const void* hptr) {
    const ushort_t* hu = (const ushort_t*)hptr;
    int bf = 1;
    for (int i = 0; i < 512; i += 2) {
        uint_t ex = (hu[i] >> 7) & 0xFFu;
        if (ex > 0x8Cu) bf = 0;  // |v| >= ~1e4 -> not bf16 data
    }
    return bf;
}
__device__ __forceinline__ int sniff_f64(const int* ei) {
    return (ei[1] == 0 && ei[3] == 0 && ei[5] == 0 && ei[7] == 0) ? 1 : 0;
}

// Merged setup: flags (block0) + zero deg + M (block0) + W_ext + optional
// h->bf16. Each block sniffs flags locally (no cross-block dependency).
__global__ __launch_bounds__(256) void setup(
    const void* __restrict__ lin_W, const void* __restrict__ lin_edge_W,
    const void* __restrict__ att_src, const void* __restrict__ att_dst,
    const void* __restrict__ att_edge, const void* __restrict__ h_in,
    const int* __restrict__ ei, float* __restrict__ Mbuf,
    ushort_t* __restrict__ wext, ushort_t* __restrict__ hbf,
    int* __restrict__ deg, int* __restrict__ flags) {
    int tid = threadIdx.x, lane = tid & 63;
    int nthreads = gridDim.x * 256;
    int gtid = blockIdx.x * 256 + tid;
    __shared__ int s_isbf;
    if (tid == 0) s_isbf = sniff_isbf(h_in);
    __syncthreads();
    int isbf = s_isbf;
    if (gtid == 0) {
        flags[0] = sniff_f64(ei);
        flags[1] = isbf;
    }
    for (int i = gtid; i < NN; i += nthreads) deg[i] = 0;
    if (blockIdx.x == 0) {
        for (int rep = 0; rep < 2; ++rep) {
            int idx = rep * 256 + tid;  // l=idx>>8, h=(idx>>6)&3, c=idx&63
            int l = idx >> 8, hc = idx & 255;
            float ae = ldx(att_edge, l * 256 + hc, isbf);
            size_t b3 = ((size_t)l * 256 + hc) * 3;
            float q0 = ae * ldx(lin_edge_W, b3 + 0, isbf);
            float q1 = ae * ldx(lin_edge_W, b3 + 1, isbf);
            float q2 = ae * ldx(lin_edge_W, b3 + 2, isbf);
            for (int off = 32; off > 0; off >>= 1) {
                q0 += __shfl_down(q0, off);
                q1 += __shfl_down(q1, off);
                q2 += __shfl_down(q2, off);
            }
            if (lane == 0) {
                int h = (idx >> 6) & 3;
                Mbuf[(l * 4 + h) * 3 + 0] = q0;
                Mbuf[(l * 4 + h) * 3 + 1] = q1;
                Mbuf[(l * 4 + h) * 3 + 2] = q2;
            }
        }
    }
    // W_ext[l][272][64]: rows 0..255 = lin_W; 256..259 = u_src[h];
    // 260..263 = u_dst[h]; 264..271 = 0
    for (int idx = gtid; idx < 2 * 272 * 64; idx += nthreads) {
        int d = idx & 63;
        int row = (idx >> 6) % 272;
        int l = idx / (272 * 64);
        float v = 0.f;
        if (row < 256) {
            v = ldx(lin_W, ((size_t)l * 256 + row) * 64 + d, isbf);
        } else if (row < 264) {
            int h = (row - 256) & 3;
            const void* att = (row < 260) ? att_src : att_dst;
            for (int c = 0; c < 64; ++c) {
                v += ldx(lin_W, ((size_t)l * 256 + h * 64 + c) * 64 + d, isbf) *
                     ldx(att, l * 256 + h * 64 + c, isbf);
            }
        }
        wext[((size_t)l * 272 + row) * 64 + d] = f2bf(v);
    }
    if (!isbf) {
        for (int i = gtid; i < NN * 64; i += nthreads)
            hbf[i] = f2bf(((const float*)h_in)[i]);
    }
}

// ---------------- CSR build ----------------

__global__ void csr_hist_pos(const int* __restrict__ ei, int* __restrict__ deg,
                             int* __restrict__ pos, const int* __restrict__ flags) {
    int e = blockIdx.x * 256 + threadIdx.x;
    if (e >= NE) return;
    pos[e] = atomicAdd(&deg[ld_dst(ei, e, flags[0])], 1);
}

__global__ __launch_bounds__(1024) void csr_scan1(const int* __restrict__ deg,
                                                  int* __restrict__ rowptr,
                                                  int* __restrict__ bsum) {
    __shared__ int sh[1024];
    int i = blockIdx.x * 1024 + threadIdx.x;
    int v = (i < NN) ? deg[i] : 0;
    sh[threadIdx.x] = v;
    __syncthreads();
    for (int off = 1; off < 1024; off <<= 1) {
        int t = (threadIdx.x >= off) ? sh[threadIdx.x - off] : 0;
        __syncthreads();
        sh[threadIdx.x] += t;
        __syncthreads();
    }
    if (i < NN) rowptr[i] = sh[threadIdx.x] - v;
    if (threadIdx.x == 1023) bsum[blockIdx.x] = sh[1023];
}

// merged scan2+scan3: each block wave-sums bsum[0..blockIdx) redundantly
__global__ __launch_bounds__(1024) void csr_scan23(int* __restrict__ rowptr,
                                                   const int* __restrict__ bsum,
                                                   int nb) {
    __shared__ int off_sh;
    int tid = threadIdx.x;
    if (tid < 64) {
        int v = (tid < blockIdx.x && tid < nb) ? bsum[tid] : 0;
        for (int off = 32; off > 0; off >>= 1) v += __shfl_down(v, off);
        if (tid == 0) off_sh = v;
    }
    __syncthreads();
    int i = blockIdx.x * 1024 + tid;
    if (i < NN) rowptr[i] += off_sh;
    if (i == 0) rowptr[NN] = NE;
}

__global__ void csr_fill(const int* __restrict__ ei, const void* __restrict__ edge_attr,
                         const int* __restrict__ rowptr, const int* __restrict__ pos,
                         float4* __restrict__ edata, const int* __restrict__ flags) {
    int e = blockIdx.x * 256 + threadIdx.x;
    if (e >= NE) return;
    int f64 = flags[0], isbf = flags[1];
    int s = ld_src(ei, e, f64), d = ld_dst(ei, e, f64);
    float4 ed;
    ed.x = ldx(edge_attr, (size_t)e * 3 + 0, isbf);
    ed.y = ldx(edge_attr, (size_t)e * 3 + 1, isbf);
    ed.z = ldx(edge_attr, (size_t)e * 3 + 2, isbf);
    ed.w = __int_as_float(s);
    edata[rowptr[d] + pos[e]] = ed;
}

// ---------------- per-layer kernels ----------------

// MFMA GEMM, wext fragments register-resident (r10-proven).
__global__ __launch_bounds__(256) void node_linear(
    const void* __restrict__ h_in, const ushort_t* __restrict__ hbf,
    const ushort_t* __restrict__ zbuf, const ushort_t* __restrict__ wext,
    ushort_t* __restrict__ xb, float* __restrict__ a_src, float* __restrict__ a_dst,
    const int* __restrict__ flags, int layer) {
    __shared__ __align__(16) ushort_t st_all[4 * 16 * SROW];  // 33792 B
    int isbf = flags[1];
    int tid = threadIdx.x, wv = tid >> 6, lane = tid & 63;
    int q = lane >> 4, mi = lane & 15;
    const ushort_t* zsrc = (layer == 0) ? (isbf ? (const ushort_t*)h_in : hbf) : zbuf;
    const ushort_t* wl = wext + (size_t)layer * 272 * 64;
    bf16x8 wf[34];
#pragma unroll
    for (int t = 0; t < 17; ++t) {
        const ushort_t* wrow = wl + (size_t)(t * 16 + mi) * 64;
        wf[2 * t]     = *(const bf16x8*)(wrow + q * 8);
        wf[2 * t + 1] = *(const bf16x8*)(wrow + 32 + q * 8);
    }
    ushort_t* st = st_all + wv * 16 * SROW;
    int gwave = blockIdx.x * 4 + wv, nwaves = gridDim.x * 4;
    for (int tile = gwave; tile < NN / 16; tile += nwaves) {
        int mbase = tile * 16, mynode = mbase + mi;
        const ushort_t* zrow = zsrc + (size_t)mynode * 64;
        bf16x8 b0 = *(const bf16x8*)(zrow + q * 8);
        bf16x8 b1 = *(const bf16x8*)(zrow + 32 + q * 8);
#pragma unroll
        for (int t = 0; t < 17; ++t) {
            f32x4 acc = {0.f, 0.f, 0.f, 0.f};
            // D col=lane&15 -> node, row=q*4+r -> wcol (verified r6/r7)
            acc = __builtin_amdgcn_mfma_f32_16x16x32_bf16(wf[2 * t], b0, acc, 0, 0, 0);
            acc = __builtin_amdgcn_mfma_f32_16x16x32_bf16(wf[2 * t + 1], b1, acc, 0, 0, 0);
            if (t < 16) {
                ushort4 pk;
                pk.x = f2bf(acc[0]);
                pk.y = f2bf(acc[1]);
                pk.z = f2bf(acc[2]);
                pk.w = f2bf(acc[3]);
                *(ushort4*)(st + mi * SROW + t * 16 + q * 4) = pk;
            } else {
                float4 av;
                av.x = acc[0]; av.y = acc[1]; av.z = acc[2]; av.w = acc[3];
                if (q == 0) *(float4*)(a_src + (size_t)mynode * 4) = av;
                else if (q == 1) *(float4*)(a_dst + (size_t)mynode * 4) = av;
            }
        }
        for (int nn = 0; nn < 16; ++nn) {
            int node = mbase + nn;
            ushort4 pk;
            pk.x = st[nn * SROW + lane];
            pk.y = st[nn * SROW + 64 + lane];
            pk.z = st[nn * SROW + 128 + lane];
            pk.w = st[nn * SROW + 192 + lane];
            *(ushort4*)(xb + (size_t)node * 256 + lane * 4) = pk;
        }
    }
}

// One wave per node; gather loop software-pipelined 8-deep for MLP.
__global__ __launch_bounds__(256) void node_aggregate(
    const int* __restrict__ rowptr, const float4* __restrict__ edata,
    const float* __restrict__ a_src, const float* __restrict__ a_dst,
    const ushort_t* __restrict__ xb, const float* __restrict__ Mbuf,
    const void* __restrict__ bias, const void* __restrict__ gamma,
    const void* __restrict__ beta, ushort_t* __restrict__ zout,
    void* __restrict__ outp, const int* __restrict__ flags, int layer, int last) {
    __shared__ float4 wsh[4][64];
    __shared__ int ssh[4][64];
    int isbf = flags[1];
    int wv = threadIdx.x >> 6;
    int lane = threadIdx.x & 63;
    int n = blockIdx.x * 4 + wv;
    float M[12];
#pragma unroll
    for (int i = 0; i < 12; ++i) M[i] = Mbuf[layer * 12 + i];
    float4 ad = *(const float4*)(a_dst + (size_t)n * 4);
    int start = rowptr[n], end = rowptr[n + 1];
    float acc0 = 0.f, acc1 = 0.f, acc2 = 0.f, acc3 = 0.f;
    float den0 = 0.f, den1 = 0.f, den2 = 0.f, den3 = 0.f;
    for (int cb = start; cb < end; cb += 64) {
        int m = end - cb;
        if (m > 64) m = 64;
        if (lane < m) {
            float4 ed = edata[cb + lane];
            int s = __float_as_int(ed.w);
            float4 as4 = *(const float4*)(a_src + (size_t)s * 4);
            float t0 = as4.x + ad.x + ed.x * M[0] + ed.y * M[1] + ed.z * M[2];
            float t1 = as4.y + ad.y + ed.x * M[3] + ed.y * M[4] + ed.z * M[5];
            float t2 = as4.z + ad.z + ed.x * M[6] + ed.y * M[7] + ed.z * M[8];
            float t3 = as4.w + ad.w + ed.x * M[9] + ed.y * M[10] + ed.z * M[11];
            t0 = t0 > 0.f ? t0 : NEG_SLOPE * t0;
            t1 = t1 > 0.f ? t1 : NEG_SLOPE * t1;
            t2 = t2 > 0.f ? t2 : NEG_SLOPE * t2;
            t3 = t3 > 0.f ? t3 : NEG_SLOPE * t3;
            float4 ex;
            ex.x = __expf(fminf(t0, 80.f));
            ex.y = __expf(fminf(t1, 80.f));
            ex.z = __expf(fminf(t2, 80.f));
            ex.w = __expf(fminf(t3, 80.f));
            wsh[wv][lane] = ex;
            ssh[wv][lane] = s;
        }
        // 8-deep pipelined gather: batch loads, then batch FMAs
        for (int j = 0; j < m; j += 8) {
            int cnt = m - j;
            if (cnt > 8) cnt = 8;
            float4 wj[8];
            ushort4 xv[8];
            if (cnt == 8) {
#pragma unroll
                for (int k = 0; k < 8; ++k) {
                    wj[k] = wsh[wv][j + k];
                    xv[k] = *(const ushort4*)(xb + (size_t)ssh[wv][j + k] * 256 + lane * 4);
                }
#pragma unroll
                for (int k = 0; k < 8; ++k) {
                    acc0 += wj[k].x * bf2f(xv[k].x);
                    acc1 += wj[k].y * bf2f(xv[k].y);
                    acc2 += wj[k].z * bf2f(xv[k].z);
                    acc3 += wj[k].w * bf2f(xv[k].w);
                    den0 += wj[k].x; den1 += wj[k].y;
                    den2 += wj[k].z; den3 += wj[k].w;
                }
            } else {
                for (int k = 0; k < cnt; ++k) {
                    wj[k] = wsh[wv][j + k];
                    xv[k] = *(const ushort4*)(xb + (size_t)ssh[wv][j + k] * 256 + lane * 4);
                }
                for (int k = 0; k < cnt; ++k) {
                    acc0 += wj[k].x * bf2f(xv[k].x);
                    acc1 += wj[k].y * bf2f(xv[k].y);
                    acc2 += wj[k].z * bf2f(xv[k].z);
                    acc3 += wj[k].w * bf2f(xv[k].w);
                    den0 += wj[k].x; den1 += wj[k].y;
                    den2 += wj[k].z; den3 += wj[k].w;
                }
            }
        }
    }
    float v = ldx(bias, layer * 64 + lane, isbf) +
              0.25f * (acc0 / (den0 + 1e-16f) + acc1 / (den1 + 1e-16f) +
                       acc2 / (den2 + 1e-16f) + acc3 / (den3 + 1e-16f));
    float sum = v;
    for (int off = 1; off < 64; off <<= 1) sum += __shfl_xor(sum, off);
    float mu = sum * (1.f / 64.f);
    float d = v - mu;
    float vv = d * d;
    for (int off = 1; off < 64; off <<= 1) vv += __shfl_xor(vv, off);
    float var = vv * (1.f / 64.f);
    float ln = d * rsqrtf(var + LN_EPS) * ldx(gamma, layer * 64 + lane, isbf) +
               ldx(beta, layer * 64 + lane, isbf);
    float sl = ln / (1.f + __expf(-ln));
    size_t idx = (size_t)n * 64 + lane;
    if (last) {
        if (isbf) ((ushort_t*)outp)[idx] = f2bf(sl);
        else      ((float*)outp)[idx] = sl;
    } else {
        zout[idx] = f2bf(sl);
    }
}

extern "C" void kernel_launch(void* const* d_in, const int* in_sizes, int n_in,
                              void* d_out, int out_size, void* d_ws, size_t ws_size,
                              hipStream_t stream) {
    int off = (in_sizes[0] == 1) ? 1 : 0;
    const void* h_in  = d_in[off + 0];
    const int*  ei    = (const int*)d_in[off + 1];
    const void* eattr = d_in[off + 2];
    const void* linW  = d_in[off + 3];
    const void* linEW = d_in[off + 4];
    const void* attS  = d_in[off + 5];
    const void* attD  = d_in[off + 6];
    const void* attE  = d_in[off + 7];
    const void* bias  = d_in[off + 8];
    const void* gamma = d_in[off + 9];
    const void* beta  = d_in[off + 10];

    // bump allocator, 256 B aligned (~56.5 MB)
    char* w = (char*)d_ws;
    size_t o = 0;
    auto alloc = [&](size_t bytes) {
        void* q = w + o;
        o += (bytes + 255) & ~(size_t)255;
        return q;
    };
    int*    flags  = (int*)alloc(8);
    float*  Mbuf   = (float*)alloc(24 * 4);
    ushort_t* wext = (ushort_t*)alloc((size_t)2 * 272 * 64 * 2);
    float*  a_src  = (float*)alloc((size_t)NN * 4 * 4);
    float*  a_dst  = (float*)alloc((size_t)NN * 4 * 4);
    int*    rowptr = (int*)alloc((size_t)(NN + 1) * 4);
    int*    deg    = (int*)alloc((size_t)NN * 4);
    int*    pos    = (int*)alloc((size_t)NE * 4);
    int*    bsum   = (int*)alloc(256 * 4);
    ushort_t* zbuf = (ushort_t*)alloc((size_t)NN * 64 * 2);
    ushort_t* hbf  = (ushort_t*)alloc((size_t)NN * 64 * 2);
    ushort_t* xb   = (ushort_t*)alloc((size_t)NN * 256 * 2);
    float4* edata  = (float4*)alloc((size_t)NE * 16);

    int nb = (NN + 1023) / 1024;  // 49
    setup<<<256, 256, 0, stream>>>(linW, linEW, attS, attD, attE, h_in, ei,
                                   Mbuf, wext, hbf, deg, flags);
    csr_hist_pos<<<(NE + 255) / 256, 256, 0, stream>>>(ei, deg, pos, flags);
    csr_scan1<<<nb, 1024, 0, stream>>>(deg, rowptr, bsum);
    csr_scan23<<<nb, 1024, 0, stream>>>(rowptr, bsum, nb);
    csr_fill<<<(NE + 255) / 256, 256, 0, stream>>>(ei, eattr, rowptr, pos, edata, flags);

    for (int l = 0; l < 2; ++l) {
        node_linear<<<512, 256, 0, stream>>>(h_in, hbf, zbuf, wext, xb,
                                             a_src, a_dst, flags, l);
        node_aggregate<<<NN / 4, 256, 0, stream>>>(rowptr, edata, a_src, a_dst,
                                                   xb, Mbuf, bias, gamma, beta,
                                                   zbuf, d_out, flags, l, l == 1);
    }
}

// Round 12
// 331.634 us; speedup vs baseline: 2.2886x; 2.2886x over previous
//
#include <hip/hip_runtime.h>
#include <math.h>

#define NN 50000
#define NE 800000
#define NEG_SLOPE 0.2f
#define LN_EPS 1e-5f
#define SROW 264  // LDS stage row stride in ushorts (256 + 8 pad)

typedef unsigned short ushort_t;
typedef unsigned int uint_t;
typedef __attribute__((ext_vector_type(8))) short bf16x8;
typedef __attribute__((ext_vector_type(4))) float f32x4;

__device__ __forceinline__ float bf2f(ushort_t u) {
    return __uint_as_float(((uint_t)u) << 16);
}
__device__ __forceinline__ ushort_t f2bf(float f) {
    uint_t b = __float_as_uint(f);
    uint_t r = (b + 0x7fffu + ((b >> 16) & 1u)) >> 16;
    return (ushort_t)r;
}
__device__ __forceinline__ float ldx(const void* p, size_t i, int isbf) {
    return isbf ? bf2f(((const ushort_t*)p)[i]) : ((const float*)p)[i];
}
__device__ __forceinline__ int clampN(int v) {
    return v < 0 ? 0 : (v >= NN ? NN - 1 : v);
}
__device__ __forceinline__ int ld_src(const int* ei, int e, int f64) {
    return clampN(f64 ? ei[2 * e] : ei[e]);
}
__device__ __forceinline__ int ld_dst(const int* ei, int e, int f64) {
    return clampN(f64 ? ei[2 * NE + 2 * e] : ei[NE + e]);
}
__device__ __forceinline__ int sniff_isbf(const void* hptr) {
    const ushort_t* hu = (const ushort_t*)hptr;
    int bf = 1;
    for (int i = 0; i < 512; i += 2) {
        uint_t ex = (hu[i] >> 7) & 0xFFu;
        if (ex > 0x8Cu) bf = 0;  // |v| >= ~1e4 -> not bf16 data
    }
    return bf;
}
__device__ __forceinline__ int sniff_f64(const int* ei) {
    return (ei[1] == 0 && ei[3] == 0 && ei[5] == 0 && ei[7] == 0) ? 1 : 0;
}

// Merged setup: flags + zero deg + M (block0) + W_ext + optional h->bf16.
__global__ __launch_bounds__(256) void setup(
    const void* __restrict__ lin_W, const void* __restrict__ lin_edge_W,
    const void* __restrict__ att_src, const void* __restrict__ att_dst,
    const void* __restrict__ att_edge, const void* __restrict__ h_in,
    const int* __restrict__ ei, float* __restrict__ Mbuf,
    ushort_t* __restrict__ wext, ushort_t* __restrict__ hbf,
    int* __restrict__ deg, int* __restrict__ flags) {
    int tid = threadIdx.x, lane = tid & 63;
    int nthreads = gridDim.x * 256;
    int gtid = blockIdx.x * 256 + tid;
    __shared__ int s_isbf;
    if (tid == 0) s_isbf = sniff_isbf(h_in);
    __syncthreads();
    int isbf = s_isbf;
    if (gtid == 0) {
        flags[0] = sniff_f64(ei);
        flags[1] = isbf;
    }
    for (int i = gtid; i < NN; i += nthreads) deg[i] = 0;
    if (blockIdx.x == 0) {
        for (int rep = 0; rep < 2; ++rep) {
            int idx = rep * 256 + tid;  // l=idx>>8, h=(idx>>6)&3, c=idx&63
            int l = idx >> 8, hc = idx & 255;
            float ae = ldx(att_edge, l * 256 + hc, isbf);
            size_t b3 = ((size_t)l * 256 + hc) * 3;
            float q0 = ae * ldx(lin_edge_W, b3 + 0, isbf);
            float q1 = ae * ldx(lin_edge_W, b3 + 1, isbf);
            float q2 = ae * ldx(lin_edge_W, b3 + 2, isbf);
            for (int off = 32; off > 0; off >>= 1) {
                q0 += __shfl_down(q0, off);
                q1 += __shfl_down(q1, off);
                q2 += __shfl_down(q2, off);
            }
            if (lane == 0) {
                int h = (idx >> 6) & 3;
                Mbuf[(l * 4 + h) * 3 + 0] = q0;
                Mbuf[(l * 4 + h) * 3 + 1] = q1;
                Mbuf[(l * 4 + h) * 3 + 2] = q2;
            }
        }
    }
    // W_ext[l][272][64]: rows 0..255 = lin_W; 256..259 = u_src[h];
    // 260..263 = u_dst[h]; 264..271 = 0
    for (int idx = gtid; idx < 2 * 272 * 64; idx += nthreads) {
        int d = idx & 63;
        int row = (idx >> 6) % 272;
        int l = idx / (272 * 64);
        float v = 0.f;
        if (row < 256) {
            v = ldx(lin_W, ((size_t)l * 256 + row) * 64 + d, isbf);
        } else if (row < 264) {
            int h = (row - 256) & 3;
            const void* att = (row < 260) ? att_src : att_dst;
            for (int c = 0; c < 64; ++c) {
                v += ldx(lin_W, ((size_t)l * 256 + h * 64 + c) * 64 + d, isbf) *
                     ldx(att, l * 256 + h * 64 + c, isbf);
            }
        }
        wext[((size_t)l * 272 + row) * 64 + d] = f2bf(v);
    }
    if (!isbf) {
        for (int i = gtid; i < NN * 64; i += nthreads)
            hbf[i] = f2bf(((const float*)h_in)[i]);
    }
}

// ---------------- CSR build ----------------

__global__ void csr_hist_pos(const int* __restrict__ ei, int* __restrict__ deg,
                             int* __restrict__ pos, const int* __restrict__ flags) {
    int e = blockIdx.x * 256 + threadIdx.x;
    if (e >= NE) return;
    pos[e] = atomicAdd(&deg[ld_dst(ei, e, flags[0])], 1);
}

__global__ __launch_bounds__(1024) void csr_scan1(const int* __restrict__ deg,
                                                  int* __restrict__ rowptr,
                                                  int* __restrict__ bsum) {
    __shared__ int sh[1024];
    int i = blockIdx.x * 1024 + threadIdx.x;
    int v = (i < NN) ? deg[i] : 0;
    sh[threadIdx.x] = v;
    __syncthreads();
    for (int off = 1; off < 1024; off <<= 1) {
        int t = (threadIdx.x >= off) ? sh[threadIdx.x - off] : 0;
        __syncthreads();
        sh[threadIdx.x] += t;
        __syncthreads();
    }
    if (i < NN) rowptr[i] = sh[threadIdx.x] - v;
    if (threadIdx.x == 1023) bsum[blockIdx.x] = sh[1023];
}

// merged scan2+scan3: each block wave-sums bsum[0..blockIdx) redundantly
__global__ __launch_bounds__(1024) void csr_scan23(int* __restrict__ rowptr,
                                                   const int* __restrict__ bsum,
                                                   int nb) {
    __shared__ int off_sh;
    int tid = threadIdx.x;
    if (tid < 64) {
        int v = (tid < blockIdx.x && tid < nb) ? bsum[tid] : 0;
        for (int off = 32; off > 0; off >>= 1) v += __shfl_down(v, off);
        if (tid == 0) off_sh = v;
    }
    __syncthreads();
    int i = blockIdx.x * 1024 + tid;
    if (i < NN) rowptr[i] += off_sh;
    if (i == 0) rowptr[NN] = NE;
}

__global__ void csr_fill(const int* __restrict__ ei, const void* __restrict__ edge_attr,
                         const int* __restrict__ rowptr, const int* __restrict__ pos,
                         float4* __restrict__ edata, const int* __restrict__ flags) {
    int e = blockIdx.x * 256 + threadIdx.x;
    if (e >= NE) return;
    int f64 = flags[0], isbf = flags[1];
    int s = ld_src(ei, e, f64), d = ld_dst(ei, e, f64);
    float4 ed;
    ed.x = ldx(edge_attr, (size_t)e * 3 + 0, isbf);
    ed.y = ldx(edge_attr, (size_t)e * 3 + 1, isbf);
    ed.z = ldx(edge_attr, (size_t)e * 3 + 2, isbf);
    ed.w = __int_as_float(s);
    edata[rowptr[d] + pos[e]] = ed;
}

// ---------------- per-layer kernels ----------------

// MFMA GEMM, wext fragments register-resident (r10-proven).
__global__ __launch_bounds__(256) void node_linear(
    const void* __restrict__ h_in, const ushort_t* __restrict__ hbf,
    const ushort_t* __restrict__ zbuf, const ushort_t* __restrict__ wext,
    ushort_t* __restrict__ xb, float* __restrict__ a_src, float* __restrict__ a_dst,
    const int* __restrict__ flags, int layer) {
    __shared__ __align__(16) ushort_t st_all[4 * 16 * SROW];  // 33792 B
    int isbf = flags[1];
    int tid = threadIdx.x, wv = tid >> 6, lane = tid & 63;
    int q = lane >> 4, mi = lane & 15;
    const ushort_t* zsrc = (layer == 0) ? (isbf ? (const ushort_t*)h_in : hbf) : zbuf;
    const ushort_t* wl = wext + (size_t)layer * 272 * 64;
    bf16x8 wf[34];
#pragma unroll
    for (int t = 0; t < 17; ++t) {
        const ushort_t* wrow = wl + (size_t)(t * 16 + mi) * 64;
        wf[2 * t]     = *(const bf16x8*)(wrow + q * 8);
        wf[2 * t + 1] = *(const bf16x8*)(wrow + 32 + q * 8);
    }
    ushort_t* st = st_all + wv * 16 * SROW;
    int gwave = blockIdx.x * 4 + wv, nwaves = gridDim.x * 4;
    for (int tile = gwave; tile < NN / 16; tile += nwaves) {
        int mbase = tile * 16, mynode = mbase + mi;
        const ushort_t* zrow = zsrc + (size_t)mynode * 64;
        bf16x8 b0 = *(const bf16x8*)(zrow + q * 8);
        bf16x8 b1 = *(const bf16x8*)(zrow + 32 + q * 8);
#pragma unroll
        for (int t = 0; t < 17; ++t) {
            f32x4 acc = {0.f, 0.f, 0.f, 0.f};
            // D col=lane&15 -> node, row=q*4+r -> wcol (verified r6/r7)
            acc = __builtin_amdgcn_mfma_f32_16x16x32_bf16(wf[2 * t], b0, acc, 0, 0, 0);
            acc = __builtin_amdgcn_mfma_f32_16x16x32_bf16(wf[2 * t + 1], b1, acc, 0, 0, 0);
            if (t < 16) {
                ushort4 pk;
                pk.x = f2bf(acc[0]);
                pk.y = f2bf(acc[1]);
                pk.z = f2bf(acc[2]);
                pk.w = f2bf(acc[3]);
                *(ushort4*)(st + mi * SROW + t * 16 + q * 4) = pk;
            } else {
                float4 av;
                av.x = acc[0]; av.y = acc[1]; av.z = acc[2]; av.w = acc[3];
                if (q == 0) *(float4*)(a_src + (size_t)mynode * 4) = av;
                else if (q == 1) *(float4*)(a_dst + (size_t)mynode * 4) = av;
            }
        }
        for (int nn = 0; nn < 16; ++nn) {
            int node = mbase + nn;
            ushort4 pk;
            pk.x = st[nn * SROW + lane];
            pk.y = st[nn * SROW + 64 + lane];
            pk.z = st[nn * SROW + 128 + lane];
            pk.w = st[nn * SROW + 192 + lane];
            *(ushort4*)(xb + (size_t)node * 256 + lane * 4) = pk;
        }
    }
}

// One wave per node; gather loop 4-deep pipelined with SCALAR registers only
// (clamped index + zeroed weight for the tail -- no dynamic private arrays,
// no scratch spill; r11's array version spilled 1 GB).
__global__ __launch_bounds__(256) void node_aggregate(
    const int* __restrict__ rowptr, const float4* __restrict__ edata,
    const float* __restrict__ a_src, const float* __restrict__ a_dst,
    const ushort_t* __restrict__ xb, const float* __restrict__ Mbuf,
    const void* __restrict__ bias, const void* __restrict__ gamma,
    const void* __restrict__ beta, ushort_t* __restrict__ zout,
    void* __restrict__ outp, const int* __restrict__ flags, int layer, int last) {
    __shared__ float4 wsh[4][64];
    __shared__ int ssh[4][64];
    int isbf = flags[1];
    int wv = threadIdx.x >> 6;
    int lane = threadIdx.x & 63;
    int n = blockIdx.x * 4 + wv;
    float M[12];
#pragma unroll
    for (int i = 0; i < 12; ++i) M[i] = Mbuf[layer * 12 + i];
    float4 ad = *(const float4*)(a_dst + (size_t)n * 4);
    int start = rowptr[n], end = rowptr[n + 1];
    float acc0 = 0.f, acc1 = 0.f, acc2 = 0.f, acc3 = 0.f;
    float den0 = 0.f, den1 = 0.f, den2 = 0.f, den3 = 0.f;
    for (int cb = start; cb < end; cb += 64) {
        int m = end - cb;
        if (m > 64) m = 64;
        if (lane < m) {
            float4 ed = edata[cb + lane];
            int s = __float_as_int(ed.w);
            float4 as4 = *(const float4*)(a_src + (size_t)s * 4);
            float t0 = as4.x + ad.x + ed.x * M[0] + ed.y * M[1] + ed.z * M[2];
            float t1 = as4.y + ad.y + ed.x * M[3] + ed.y * M[4] + ed.z * M[5];
            float t2 = as4.z + ad.z + ed.x * M[6] + ed.y * M[7] + ed.z * M[8];
            float t3 = as4.w + ad.w + ed.x * M[9] + ed.y * M[10] + ed.z * M[11];
            t0 = t0 > 0.f ? t0 : NEG_SLOPE * t0;
            t1 = t1 > 0.f ? t1 : NEG_SLOPE * t1;
            t2 = t2 > 0.f ? t2 : NEG_SLOPE * t2;
            t3 = t3 > 0.f ? t3 : NEG_SLOPE * t3;
            float4 ex;
            ex.x = __expf(fminf(t0, 80.f));
            ex.y = __expf(fminf(t1, 80.f));
            ex.z = __expf(fminf(t2, 80.f));
            ex.w = __expf(fminf(t3, 80.f));
            wsh[wv][lane] = ex;
            ssh[wv][lane] = s;
        }
        for (int j = 0; j < m; j += 4) {
            // clamped indices; invalid slots get zero weight (scalars only)
            int j1 = j + 1 < m ? j + 1 : m - 1;
            int j2 = j + 2 < m ? j + 2 : m - 1;
            int j3 = j + 3 < m ? j + 3 : m - 1;
            int s0 = ssh[wv][j],  s1 = ssh[wv][j1];
            int s2 = ssh[wv][j2], s3 = ssh[wv][j3];
            float4 w0 = wsh[wv][j];
            float4 w1 = wsh[wv][j1];
            float4 w2 = wsh[wv][j2];
            float4 w3 = wsh[wv][j3];
            if (j + 1 >= m) w1 = make_float4(0.f, 0.f, 0.f, 0.f);
            if (j + 2 >= m) w2 = make_float4(0.f, 0.f, 0.f, 0.f);
            if (j + 3 >= m) w3 = make_float4(0.f, 0.f, 0.f, 0.f);
            ushort4 x0 = *(const ushort4*)(xb + (size_t)s0 * 256 + lane * 4);
            ushort4 x1 = *(const ushort4*)(xb + (size_t)s1 * 256 + lane * 4);
            ushort4 x2 = *(const ushort4*)(xb + (size_t)s2 * 256 + lane * 4);
            ushort4 x3 = *(const ushort4*)(xb + (size_t)s3 * 256 + lane * 4);
            acc0 += w0.x * bf2f(x0.x) + w1.x * bf2f(x1.x) +
                    w2.x * bf2f(x2.x) + w3.x * bf2f(x3.x);
            acc1 += w0.y * bf2f(x0.y) + w1.y * bf2f(x1.y) +
                    w2.y * bf2f(x2.y) + w3.y * bf2f(x3.y);
            acc2 += w0.z * bf2f(x0.z) + w1.z * bf2f(x1.z) +
                    w2.z * bf2f(x2.z) + w3.z * bf2f(x3.z);
            acc3 += w0.w * bf2f(x0.w) + w1.w * bf2f(x1.w) +
                    w2.w * bf2f(x2.w) + w3.w * bf2f(x3.w);
            den0 += w0.x + w1.x + w2.x + w3.x;
            den1 += w0.y + w1.y + w2.y + w3.y;
            den2 += w0.z + w1.z + w2.z + w3.z;
            den3 += w0.w + w1.w + w2.w + w3.w;
        }
    }
    float v = ldx(bias, layer * 64 + lane, isbf) +
              0.25f * (acc0 / (den0 + 1e-16f) + acc1 / (den1 + 1e-16f) +
                       acc2 / (den2 + 1e-16f) + acc3 / (den3 + 1e-16f));
    float sum = v;
    for (int off = 1; off < 64; off <<= 1) sum += __shfl_xor(sum, off);
    float mu = sum * (1.f / 64.f);
    float d = v - mu;
    float vv = d * d;
    for (int off = 1; off < 64; off <<= 1) vv += __shfl_xor(vv, off);
    float var = vv * (1.f / 64.f);
    float ln = d * rsqrtf(var + LN_EPS) * ldx(gamma, layer * 64 + lane, isbf) +
               ldx(beta, layer * 64 + lane, isbf);
    float sl = ln / (1.f + __expf(-ln));
    size_t idx = (size_t)n * 64 + lane;
    if (last) {
        if (isbf) ((ushort_t*)outp)[idx] = f2bf(sl);
        else      ((float*)outp)[idx] = sl;
    } else {
        zout[idx] = f2bf(sl);
    }
}

extern "C" void kernel_launch(void* const* d_in, const int* in_sizes, int n_in,
                              void* d_out, int out_size, void* d_ws, size_t ws_size,
                              hipStream_t stream) {
    int off = (in_sizes[0] == 1) ? 1 : 0;
    const void* h_in  = d_in[off + 0];
    const int*  ei    = (const int*)d_in[off + 1];
    const void* eattr = d_in[off + 2];
    const void* linW  = d_in[off + 3];
    const void* linEW = d_in[off + 4];
    const void* attS  = d_in[off + 5];
    const void* attD  = d_in[off + 6];
    const void* attE  = d_in[off + 7];
    const void* bias  = d_in[off + 8];
    const void* gamma = d_in[off + 9];
    const void* beta  = d_in[off + 10];

    // bump allocator, 256 B aligned (~56.5 MB)
    char* w = (char*)d_ws;
    size_t o = 0;
    auto alloc = [&](size_t bytes) {
        void* q = w + o;
        o += (bytes + 255) & ~(size_t)255;
        return q;
    };
    int*    flags  = (int*)alloc(8);
    float*  Mbuf   = (float*)alloc(24 * 4);
    ushort_t* wext = (ushort_t*)alloc((size_t)2 * 272 * 64 * 2);
    float*  a_src  = (float*)alloc((size_t)NN * 4 * 4);
    float*  a_dst  = (float*)alloc((size_t)NN * 4 * 4);
    int*    rowptr = (int*)alloc((size_t)(NN + 1) * 4);
    int*    deg    = (int*)alloc((size_t)NN * 4);
    int*    pos    = (int*)alloc((size_t)NE * 4);
    int*    bsum   = (int*)alloc(256 * 4);
    ushort_t* zbuf = (ushort_t*)alloc((size_t)NN * 64 * 2);
    ushort_t* hbf  = (ushort_t*)alloc((size_t)NN * 64 * 2);
    ushort_t* xb   = (ushort_t*)alloc((size_t)NN * 256 * 2);
    float4* edata  = (float4*)alloc((size_t)NE * 16);

    int nb = (NN + 1023) / 1024;  // 49
    setup<<<256, 256, 0, stream>>>(linW, linEW, attS, attD, attE, h_in, ei,
                                   Mbuf, wext, hbf, deg, flags);
    csr_hist_pos<<<(NE + 255) / 256, 256, 0, stream>>>(ei, deg, pos, flags);
    csr_scan1<<<nb, 1024, 0, stream>>>(deg, rowptr, bsum);
    csr_scan23<<<nb, 1024, 0, stream>>>(rowptr, bsum, nb);
    csr_fill<<<(NE + 255) / 256, 256, 0, stream>>>(ei, eattr, rowptr, pos, edata, flags);

    for (int l = 0; l < 2; ++l) {
        node_linear<<<512, 256, 0, stream>>>(h_in, hbf, zbuf, wext, xb,
                                             a_src, a_dst, flags, l);
        node_aggregate<<<NN / 4, 256, 0, stream>>>(rowptr, edata, a_src, a_dst,
                                                   xb, Mbuf, bias, gamma, beta,
                                                   zbuf, d_out, flags, l, l == 1);
    }
}